// Round 1
// baseline (2612.563 us; speedup 1.0000x reference)
//
#include <hip/hip_runtime.h>

// dense_baens: out[n,e] = sum_d x[n,d] * U[n,d,e] + bias[n,0,e]
// N=2048, D1=512, D2=512, all fp32.
// Memory-bound: U = 2.147 GB streamed once. Target ~345 us at 6.3 TB/s.

constexpr int N  = 2048;
constexpr int D1 = 512;
constexpr int D2 = 512;

// Block = 128 threads (2 waves). blockIdx.x = sample n.
// Thread t owns columns [4t, 4t+4) of out[n] (float4).
// Per d-iteration the block reads one contiguous 2KB row of U[n] -> the
// whole 1MB U[n] slab is streamed fully sequentially (perfect coalescing).
__global__ __launch_bounds__(128) void baens_gemv_kernel(
    const float* __restrict__ x,
    const float* __restrict__ U,
    const float* __restrict__ bias,
    float* __restrict__ out)
{
    __shared__ float xs[D1];

    const int n = blockIdx.x;
    const int t = threadIdx.x;  // 0..127

    // Stage x[n] (512 floats = 2KB) into LDS: 128 threads x float4.
    const float4* xg = reinterpret_cast<const float4*>(x + (size_t)n * D1);
    reinterpret_cast<float4*>(xs)[t] = xg[t];
    __syncthreads();

    // U[n] base, offset to this thread's column quad.
    const float4* Urow =
        reinterpret_cast<const float4*>(U + (size_t)n * D1 * D2) + t;

    float4 acc = make_float4(0.f, 0.f, 0.f, 0.f);

    // Unroll by 8: 8 independent float4 loads in flight per thread.
    #pragma unroll 8
    for (int d = 0; d < D1; ++d) {
        const float xv = xs[d];                       // LDS broadcast (free)
        const float4 u = Urow[(size_t)d * (D2 / 4)];  // coalesced 16B/lane
        acc.x += xv * u.x;
        acc.y += xv * u.y;
        acc.z += xv * u.z;
        acc.w += xv * u.w;
    }

    const float4 b =
        reinterpret_cast<const float4*>(bias + (size_t)n * D2)[t];
    float4 o;
    o.x = acc.x + b.x;
    o.y = acc.y + b.y;
    o.z = acc.z + b.z;
    o.w = acc.w + b.w;
    reinterpret_cast<float4*>(out + (size_t)n * D2)[t] = o;
}

extern "C" void kernel_launch(void* const* d_in, const int* in_sizes, int n_in,
                              void* d_out, int out_size, void* d_ws, size_t ws_size,
                              hipStream_t stream) {
    const float* x    = (const float*)d_in[0];  // (N, D1)
    const float* U    = (const float*)d_in[1];  // (N, D1, D2)
    const float* bias = (const float*)d_in[2];  // (N, 1, D2)
    float* out        = (float*)d_out;          // (N, D2)

    baens_gemv_kernel<<<N, 128, 0, stream>>>(x, U, bias, out);
}